// Round 1
// baseline (1003.653 us; speedup 1.0000x reference)
//
#include <hip/hip_runtime.h>
#include <math.h>

#define NROWS 131072
#define DDIM  512
#define BB    32
#define SS    128
#define KK    8

// ---------------------------------------------------------------------------
// q[b][d] = mean_s query[b][s][d]
// 256 blocks (b, dchunk) x 256 thr; s split 4 ways across waves -> 4 waves/CU.
__global__ __launch_bounds__(256) void k_qmean(const float* __restrict__ query,
                                               float* __restrict__ q) {
  __shared__ float part[256];
  int b  = blockIdx.x >> 3;            // 32 b
  int dc = blockIdx.x & 7;             // 8 d-chunks of 64
  int t  = threadIdx.x;
  int lane = t & 63;
  int p    = t >> 6;                   // s-quarter 0..3
  const float* src = query + (size_t)b * SS * DDIM + (size_t)(p * 32) * DDIM
                   + dc * 64 + lane;
  float s = 0.f;
  #pragma unroll 8
  for (int i = 0; i < 32; ++i) s += src[(size_t)i * DDIM];
  part[t] = s;
  __syncthreads();
  if (t < 64) {
    float tot = part[t] + part[64 + t] + part[128 + t] + part[192 + t];
    q[b * DDIM + dc * 64 + t] = tot * (1.0f / 128.0f);
  }
}

// ---------------------------------------------------------------------------
// FUSED: newmem[r][:] = base[r][:] + A[r][:] @ B      (bit-identical to k_mem)
//        scores[b][r] = q[b][:] . newmem[r][:]        (bit-identical to k_scores)
// 1 thread = 1 row. q staged in LDS (64 KB -> 2 blocks/CU); B reads are
// wave-uniform (scalar path); A row in 16 VGPRs; explicit 4-deep prefetch of
// base keeps >=4 float4 loads in flight per wave (k_mem was 1-deep -> 2.3 TB/s).
__global__ __launch_bounds__(256) void k_memscores(const float* __restrict__ base,
                                                   const float* __restrict__ A,
                                                   const float* __restrict__ Bm,
                                                   const float* __restrict__ q,
                                                   float* __restrict__ newmem,
                                                   float* __restrict__ scores) {
  __shared__ float4 sq[4096];                 // 32 b * 128 d4 = 64 KB
  int t = threadIdx.x;
  const float4* qg = (const float4*)q;
  #pragma unroll
  for (int u = 0; u < 16; ++u) sq[u * 256 + t] = qg[u * 256 + t];
  __syncthreads();

  int r = blockIdx.x * 256 + t;

  // A row -> registers (lanes read adjacent 64B rows: 4 KB contiguous / wave)
  const float* Ar = A + (size_t)r * 16;
  float av[16];
  #pragma unroll
  for (int j = 0; j < 4; ++j) {
    float4 a = *(const float4*)(Ar + 4 * j);
    av[4 * j]     = a.x; av[4 * j + 1] = a.y;
    av[4 * j + 2] = a.z; av[4 * j + 3] = a.w;
  }

  float acc[32];
  #pragma unroll
  for (int b = 0; b < 32; ++b) acc[b] = 0.f;

  const float4* brow = (const float4*)(base + (size_t)r * DDIM);
  float4*       nrow = (float4*)(newmem + (size_t)r * DDIM);

  // software pipeline: group of 4 d4's; issue next group's loads before use
  float4 cur0 = brow[0], cur1 = brow[1], cur2 = brow[2], cur3 = brow[3];

  for (int g = 0; g < 32; ++g) {
    int nb = (g < 31) ? 4 * (g + 1) : 0;      // last iter: harmless reload of 0
    float4 nxt0 = brow[nb];
    float4 nxt1 = brow[nb + 1];
    float4 nxt2 = brow[nb + 2];
    float4 nxt3 = brow[nb + 3];

    #pragma unroll
    for (int j = 0; j < 4; ++j) {
      int d4 = 4 * g + j;
      float4 m = (j == 0) ? cur0 : (j == 1) ? cur1 : (j == 2) ? cur2 : cur3;
      // lora: B slice is wave-uniform -> scalar loads, K$/L2 resident (32 KB)
      #pragma unroll
      for (int rr = 0; rr < 16; ++rr) {
        float4 bv = *(const float4*)(Bm + rr * DDIM + 4 * d4);
        m.x += av[rr] * bv.x; m.y += av[rr] * bv.y;
        m.z += av[rr] * bv.z; m.w += av[rr] * bv.w;
      }
      nrow[d4] = m;
      // scores: q broadcast from LDS, 32x register reuse of m
      #pragma unroll
      for (int b = 0; b < 32; ++b) {
        float4 qv = sq[b * 128 + d4];
        acc[b] += qv.x * m.x + qv.y * m.y + qv.z * m.z + qv.w * m.w;
      }
    }
    cur0 = nxt0; cur1 = nxt1; cur2 = nxt2; cur3 = nxt3;
  }

  #pragma unroll
  for (int b = 0; b < 32; ++b) scores[(size_t)b * NROWS + r] = acc[b];
}

// ---------------------------------------------------------------------------
// top-k comparator: descending by score, ties -> lower index (lax.top_k)
__device__ __forceinline__ void insert8(float (&v)[8], int (&ix)[8], float x, int i) {
  bool better = (x > v[7]) || (x == v[7] && i < ix[7]);
  if (!better) return;
  v[7] = x; ix[7] = i;
  #pragma unroll
  for (int u = 7; u > 0; --u) {
    bool sw = (v[u] > v[u-1]) || (v[u] == v[u-1] && ix[u] < ix[u-1]);
    if (sw) {
      float tv = v[u]; v[u] = v[u-1]; v[u-1] = tv;
      int ti = ix[u]; ix[u] = ix[u-1]; ix[u-1] = ti;
    }
  }
}

// stage 1: grid (32 b x 16 j); block scans 8192 rows -> 8 candidates
__global__ __launch_bounds__(256) void k_topk1(const float* __restrict__ scores,
                                               float* __restrict__ cval,
                                               int* __restrict__ cidx) {
  __shared__ float lval[256][8]; __shared__ int lidx[256][8];
  __shared__ float mval[32][8];  __shared__ int midx[32][8];
  int b = blockIdx.x >> 4, j = blockIdx.x & 15, t = threadIdx.x;
  const float4* s4 = (const float4*)(scores + (size_t)b * NROWS + j * 8192);

  float v[8]; int ix[8];
  #pragma unroll
  for (int e = 0; e < 8; ++e) { v[e] = -1e30f; ix[e] = 0x7fffffff; }
  #pragma unroll
  for (int i = 0; i < 8; ++i) {
    int f4 = i * 256 + t;                     // float4 index in chunk
    float4 x = s4[f4];
    int n0 = j * 8192 + f4 * 4;
    insert8(v, ix, x.x, n0);
    insert8(v, ix, x.y, n0 + 1);
    insert8(v, ix, x.z, n0 + 2);
    insert8(v, ix, x.w, n0 + 3);
  }
  #pragma unroll
  for (int e = 0; e < 8; ++e) { lval[t][e] = v[e]; lidx[t][e] = ix[e]; }
  __syncthreads();

  if (t < 32) {
    float mv[8]; int mi[8];
    #pragma unroll
    for (int e = 0; e < 8; ++e) { mv[e] = -1e30f; mi[e] = 0x7fffffff; }
    for (int u = 0; u < 8; ++u) {
      int src = t * 8 + u;
      #pragma unroll
      for (int e = 0; e < 8; ++e) insert8(mv, mi, lval[src][e], lidx[src][e]);
    }
    #pragma unroll
    for (int e = 0; e < 8; ++e) { mval[t][e] = mv[e]; midx[t][e] = mi[e]; }
  }
  __syncthreads();

  if (t == 0) {
    float mv[8]; int mi[8];
    #pragma unroll
    for (int e = 0; e < 8; ++e) { mv[e] = -1e30f; mi[e] = 0x7fffffff; }
    for (int u = 0; u < 32; ++u)
      #pragma unroll
      for (int e = 0; e < 8; ++e) insert8(mv, mi, mval[u][e], midx[u][e]);
    #pragma unroll
    for (int e = 0; e < 8; ++e) {
      cval[(b * 16 + j) * 8 + e] = mv[e];
      cidx[(b * 16 + j) * 8 + e] = mi[e];
    }
  }
}

// ---------------------------------------------------------------------------
// stage-2 merge (128 candidates -> top-8) fused with gather:
// retrieved[b][k][:] = mem[topidx[b][k]][:]; x[b][:] = sum_k retrieved
__global__ __launch_bounds__(128) void k_gather(const float* __restrict__ mem,
                                                const float* __restrict__ cval,
                                                const int* __restrict__ cidx,
                                                int* __restrict__ topidx,
                                                float* __restrict__ retrieved,
                                                float* __restrict__ x) {
  __shared__ float scv[128]; __shared__ int sci[128];
  __shared__ int stop[8];
  int b = blockIdx.x, t = threadIdx.x;   // t in [0,128)
  scv[t] = cval[b * 128 + t];
  sci[t] = cidx[b * 128 + t];
  __syncthreads();
  if (t == 0) {
    float mv[8]; int mi[8];
    #pragma unroll
    for (int e = 0; e < 8; ++e) { mv[e] = -1e30f; mi[e] = 0x7fffffff; }
    for (int u = 0; u < 128; ++u) insert8(mv, mi, scv[u], sci[u]);
    #pragma unroll
    for (int e = 0; e < 8; ++e) { stop[e] = mi[e]; topidx[b * 8 + e] = mi[e]; }
  }
  __syncthreads();

  float4 xs = make_float4(0.f, 0.f, 0.f, 0.f);
  #pragma unroll
  for (int k = 0; k < 8; ++k) {
    int row = stop[k];
    float4 vv = *(const float4*)(mem + (size_t)row * DDIM + 4 * t);
    *(float4*)(retrieved + (size_t)(b * 8 + k) * DDIM + 4 * t) = vv;
    xs.x += vv.x; xs.y += vv.y; xs.z += vv.z; xs.w += vv.w;
  }
  *(float4*)(x + (size_t)b * DDIM + 4 * t) = xs;
}

// ---------------------------------------------------------------------------
// GRU cell with h0 = 0:  gh = b_hh, so w_hh GEMM vanishes.
__global__ __launch_bounds__(512) void k_gru(const float* __restrict__ x,
                                             const float* __restrict__ wih,
                                             const float* __restrict__ bih,
                                             const float* __restrict__ bhh,
                                             const float* __restrict__ wgw,
                                             const float* __restrict__ wgb,
                                             float* __restrict__ hidden,
                                             float* __restrict__ pws) {
  __shared__ float sx[512];
  __shared__ float sred[8];
  int b = blockIdx.x, t = threadIdx.x;
  sx[t] = x[b * 512 + t];
  __syncthreads();
  const float* wr = wih + (size_t)t * 512;
  const float* wz = wih + (size_t)(512 + t) * 512;
  const float* wn = wih + (size_t)(1024 + t) * 512;
  float gr = 0.f, gz = 0.f, gn = 0.f;
  #pragma unroll 4
  for (int d4 = 0; d4 < 128; ++d4) {
    float4 xv = *(const float4*)(sx + 4 * d4);   // broadcast
    float4 a = *(const float4*)(wr + 4 * d4);
    float4 c = *(const float4*)(wz + 4 * d4);
    float4 e = *(const float4*)(wn + 4 * d4);
    gr += a.x*xv.x + a.y*xv.y + a.z*xv.z + a.w*xv.w;
    gz += c.x*xv.x + c.y*xv.y + c.z*xv.z + c.w*xv.w;
    gn += e.x*xv.x + e.y*xv.y + e.z*xv.z + e.w*xv.w;
  }
  float r = 1.f / (1.f + expf(-(gr + bih[t]        + bhh[t])));
  float z = 1.f / (1.f + expf(-(gz + bih[512 + t]  + bhh[512 + t])));
  float n = tanhf(gn + bih[1024 + t] + r * bhh[1024 + t]);
  float h = (1.f - z) * n;
  hidden[b * 512 + t] = h;

  float pw = h * wgw[t];
  #pragma unroll
  for (int off = 32; off > 0; off >>= 1) pw += __shfl_down(pw, off, 64);
  if ((t & 63) == 0) sred[t >> 6] = pw;
  __syncthreads();
  if (t == 0) {
    float ssum = 0.f;
    #pragma unroll
    for (int j = 0; j < 8; ++j) ssum += sred[j];
    pws[b] = 1.f / (1.f + expf(-(ssum + wgb[0])));
  }
}

// ---------------------------------------------------------------------------
// Sequential-over-batch scatter: new_mem[row] = (1-p)*new_mem[row] + p*q[b]
__global__ __launch_bounds__(256) void k_scatter(float* __restrict__ newmem,
                                                 const int* __restrict__ topidx,
                                                 const float* __restrict__ pws,
                                                 const float* __restrict__ q) {
  int t = threadIdx.x;
  int d = blockIdx.x * 64 + (t & 63);    // 8 blocks x 64 d = 512
  int k0 = t >> 6;                       // 0..3
  for (int b = 0; b < 32; ++b) {
    float p = pws[b];
    float qv = q[b * 512 + d];
    #pragma unroll
    for (int kk = 0; kk < 2; ++kk) {
      int k = k0 + kk * 4;
      int row = topidx[b * 8 + k];
      size_t off = (size_t)row * 512 + d;
      float m = __hip_atomic_load(newmem + off, __ATOMIC_RELAXED,
                                  __HIP_MEMORY_SCOPE_AGENT);
      __hip_atomic_store(newmem + off, (1.f - p) * m + p * qv,
                         __ATOMIC_RELAXED, __HIP_MEMORY_SCOPE_AGENT);
    }
    __syncthreads();
  }
}

// ---------------------------------------------------------------------------
extern "C" void kernel_launch(void* const* d_in, const int* in_sizes, int n_in,
                              void* d_out, int out_size, void* d_ws, size_t ws_size,
                              hipStream_t stream) {
  const float* query = (const float*)d_in[0];
  const float* base  = (const float*)d_in[1];
  const float* lA    = (const float*)d_in[2];
  const float* lB    = (const float*)d_in[3];
  const float* wih   = (const float*)d_in[4];
  // d_in[5] = gru_w_hh: unused (h0 == 0)
  const float* bih   = (const float*)d_in[6];
  const float* bhh   = (const float*)d_in[7];
  const float* wgw   = (const float*)d_in[8];
  const float* wgb   = (const float*)d_in[9];

  float* out = (float*)d_out;
  float* retrieved = out;                    // 32*8*512   = 131072
  float* hidden    = out + 131072;           // 32*512     = 16384
  float* newmem    = out + 147456;           // 131072*512 = 67108864

  float* wq  = (float*)d_ws;                 // 16384
  float* wsc = wq + 16384;                   // 32*131072 = 4194304
  float* wx  = wsc + 4194304;                // 16384
  float* wp  = wx + 16384;                   // 32
  int*   wti = (int*)(wp + 32);              // 256
  float* wcv = (float*)(wti + 256);          // 32*16*8 = 4096
  int*   wci = (int*)(wcv + 4096);           // 4096

  k_qmean    <<<256, 256, 0, stream>>>(query, wq);
  k_memscores<<<512, 256, 0, stream>>>(base, lA, lB, wq, newmem, wsc);
  k_topk1    <<<512, 256, 0, stream>>>(wsc, wcv, wci);
  k_gather   <<<32,  128, 0, stream>>>(newmem, wcv, wci, wti, retrieved, wx);
  k_gru      <<<32,  512, 0, stream>>>(wx, wih, bih, bhh, wgw, wgb, hidden, wp);
  k_scatter  <<<8,   256, 0, stream>>>(newmem, wti, wp, wq);
}